// Round 10
// baseline (616.295 us; speedup 1.0000x reference)
//
#include <hip/hip_runtime.h>
#include <hip/hip_bf16.h>
#include <stdint.h>

#define NNODES 100000
#define HID 128
#define TSZ 32
#define MDIM 16
#define ES 600000
#define ED 600000
#define ETOT (ES + ED)
#define GN (2 * NNODES)     // both branches share one node index space
#define GNP 200704          // 196 * 1024, padded for the scan
#define SCAN_BLOCKS 196
#define NP8 (NNODES * 8)    // 800,000 packed pairs per branch
#define GN8 (GN * 8)        // 1,600,000 packed pairs total
#define PQ_BLOCKS 1563      // ceil(NNODES/64)
#define CNT_BLK 586         // ceil(600000/1024) count blocks per edge set
#define PROP_NB 1024        // co-resident blocks for k_prop (4/CU guaranteed)

typedef unsigned short ushort_t;

__device__ __forceinline__ float bflo(unsigned u) { return __uint_as_float(u << 16); }
__device__ __forceinline__ float bfhi(unsigned u) { return __uint_as_float(u & 0xffff0000u); }

// RNE fp32 -> bf16 (finite inputs only)
__device__ __forceinline__ unsigned f2bf(float f) {
    unsigned u = __float_as_uint(f);
    return (u + 0x7FFFu + ((u >> 16) & 1u)) >> 16;
}
__device__ __forceinline__ unsigned packbf(float lo, float hi) {
    return f2bf(lo) | (f2bf(hi) << 16);
}

__device__ __forceinline__ float tanh_fast(float v) {
    float z = __expf(2.f * v);
    return 1.f - 2.f / (z + 1.f);
}

// ---------------------------------------------------------------- PQ (int8, step 1/32)
__global__ __launch_bounds__(256) void k_pq(const float* __restrict__ x,
                                            const float* __restrict__ Wt,
                                            const float* __restrict__ bt,
                                            char* __restrict__ pq) {
    __shared__ float xs[64][132];
    __shared__ float wl[64][130];
    const int tid = threadIdx.x;
    const int n0 = blockIdx.x * 64;

    for (int i = tid; i < 4096; i += 256) {
        int h = i >> 5, c = i & 31;
        float a = Wt[i];
        float b = Wt[4096 + i];
        wl[c][h] = a;
        wl[c + 32][h] = b;
    }
    const float4* xsrc = (const float4*)(x + (size_t)n0 * 128);
#pragma unroll
    for (int i = 0; i < 8; ++i) {
        int idx = tid + 256 * i;
        int node = idx >> 5;
        int rem = idx & 31;
        if (n0 + node < NNODES) {
            float4 v = xsrc[idx];
            *(float4*)&xs[node][rem * 4] = v;
        }
    }
    __syncthreads();

    const int l = tid & 63;
    const int w = tid >> 6;
    const int c0 = l & 15;
    const int ng = w * 16 + (l >> 4) * 4;
    float acc[4][4] = {};
#pragma unroll 4
    for (int h = 0; h < 128; h += 2) {
        float2 xv[4], wv[4];
#pragma unroll
        for (int m = 0; m < 4; ++m) xv[m] = *(const float2*)&xs[ng + m][h];
#pragma unroll
        for (int m = 0; m < 4; ++m) wv[m] = *(const float2*)&wl[c0 + 16 * m][h];
#pragma unroll
        for (int a = 0; a < 4; ++a)
#pragma unroll
            for (int b = 0; b < 4; ++b)
                acc[a][b] = fmaf(xv[a].y, wv[b].y, fmaf(xv[a].x, wv[b].x, acc[a][b]));
    }
    float bv[4];
#pragma unroll
    for (int b = 0; b < 4; ++b) {
        int c = c0 + 16 * b;
        bv[b] = (c < 32) ? bt[c] : 0.f;
    }
    __syncthreads();
    char* buf = (char*)&xs[0][0];
#pragma unroll
    for (int a = 0; a < 4; ++a) {
#pragma unroll
        for (int b = 0; b < 4; ++b) {
            float v = acc[a][b] + bv[b];
            int q = __float2int_rn(v * 32.f);
            q = max(-127, min(127, q));
            buf[(ng + a) * 64 + c0 + 16 * b] = (char)q;
        }
    }
    __syncthreads();
    uint4 v4 = ((const uint4*)buf)[tid];
    ((uint4*)(pq + (size_t)blockIdx.x * 4096))[tid] = v4;
}

// ---------------------------------------------------------------- init m + degree count (merged)
__global__ __launch_bounds__(256) void k_initcount(const float* __restrict__ mask,
                                                   unsigned* __restrict__ m_a,
                                                   const int* __restrict__ sdst,
                                                   const int* __restrict__ ddst,
                                                   int* __restrict__ counts) {
    const int tid = threadIdx.x;
    int b = (int)blockIdx.x;
    if (b < 3125) {
        int idx = b * 256 + tid;           // < NP8 exactly
        float2 v = ((const float2*)mask)[idx];
        unsigned p = packbf(v.x, v.y);
        m_a[idx] = p;
        m_a[NP8 + idx] = p;
        return;
    }
    b -= 3125;
    const int* dst;
    int add;
    if (b < CNT_BLK) { dst = sdst; add = 0; }
    else { b -= CNT_BLK; dst = ddst; add = NNODES; }
    int e0 = (b * 256 + tid) * 4;
    if (e0 + 4 <= 600000) {
        int4 d = *(const int4*)(dst + e0);
        atomicAdd(&counts[d.x + add], 1);
        atomicAdd(&counts[d.y + add], 1);
        atomicAdd(&counts[d.z + add], 1);
        atomicAdd(&counts[d.w + add], 1);
    } else {
        for (int e = e0; e < 600000; ++e) atomicAdd(&counts[dst[e] + add], 1);
    }
}

// ---------------------------------------------------------------- fused scan (single kernel, arrive-and-spin)
__global__ __launch_bounds__(256) void k_scanfused(const int* __restrict__ counts,
                                                   int* __restrict__ bsum,
                                                   int* __restrict__ flag,
                                                   int* __restrict__ off,
                                                   int* __restrict__ cursor) {
    __shared__ int sh[256];
    const int tid = threadIdx.x;
    const int bid = (int)blockIdx.x;
    int4 v = ((const int4*)counts)[bid * 256 + tid];
    int tot = v.x + v.y + v.z + v.w;
    sh[tid] = tot;
    __syncthreads();
    for (int o = 1; o < 256; o <<= 1) {
        int add = (tid >= o) ? sh[tid - o] : 0;
        __syncthreads();
        sh[tid] += add;
        __syncthreads();
    }
    int incl = sh[tid];
    if (tid == 255) bsum[bid] = incl;
    if (tid == 0) {
        __threadfence();
        atomicAdd(flag, 1);
        while (__hip_atomic_load(flag, __ATOMIC_RELAXED, __HIP_MEMORY_SCOPE_AGENT) < SCAN_BLOCKS) {}
        __threadfence();
    }
    __syncthreads();
    sh[tid] = (tid < SCAN_BLOCKS) ? bsum[tid] : 0;
    __syncthreads();
    for (int o = 1; o < 256; o <<= 1) {
        int add = (tid >= o) ? sh[tid - o] : 0;
        __syncthreads();
        sh[tid] += add;
        __syncthreads();
    }
    int base = (bid > 0) ? sh[bid - 1] : 0;
    int excl = base + incl - tot;
    int4 o4;
    o4.x = excl;
    o4.y = o4.x + v.x;
    o4.z = o4.y + v.y;
    o4.w = o4.z + v.z;
    ((int4*)off)[bid * 256 + tid] = o4;
    ((int4*)cursor)[bid * 256 + tid] = o4;
}

// ---------------------------------------------------------------- ew + CSR fill
__global__ void k_ewfill(const char* __restrict__ pq,
                         const int* __restrict__ ssrc, const int* __restrict__ sdst,
                         const int* __restrict__ dsrc, const int* __restrict__ ddst,
                         const float* __restrict__ sattr, const float* __restrict__ dattr,
                         const float* __restrict__ Wp, const float* __restrict__ bp,
                         const float* __restrict__ Wd, const float* __restrict__ bd,
                         int* __restrict__ cursor, unsigned* __restrict__ csr) {
    int e = blockIdx.x * 256 + threadIdx.x;
    if (e >= ETOT) return;
    int src, dst, dstg, srcg;
    float acc;
    const float* wt;
    if (e < ES) {
        src = ssrc[e];
        dst = sdst[e];
        dstg = dst;
        srcg = src;
        const float4 a = *(const float4*)(sattr + (size_t)e * 4);
        acc = bp[0] + a.x * Wp[0] + a.y * Wp[1] + a.z * Wp[2] + a.w * Wp[3];
        wt = Wp + 4;
    } else {
        int ed = e - ES;
        src = dsrc[ed];
        dst = ddst[ed];
        dstg = dst + NNODES;
        srcg = src + NNODES;
        acc = bd[0] + dattr[ed] * Wd[0];
        wt = Wd + 1;
    }
    const uint4* Pp = (const uint4*)(pq + (size_t)src * 64);
    const uint4* Qp = (const uint4*)(pq + (size_t)dst * 64 + 32);
    uint4 pa = Pp[0], pb = Pp[1];
    uint4 qa = Qp[0], qb = Qp[1];
    unsigned pw[8] = {pa.x, pa.y, pa.z, pa.w, pb.x, pb.y, pb.z, pb.w};
    unsigned qw[8] = {qa.x, qa.y, qa.z, qa.w, qb.x, qb.y, qb.z, qb.w};
#pragma unroll
    for (int d = 0; d < 8; ++d) {
        unsigned a = pw[d], b = qw[d];
#pragma unroll
        for (int k = 0; k < 4; ++k) {
            int pi = (int)(char)(a >> (8 * k));
            int qi = (int)(char)(b >> (8 * k));
            float t = tanh_fast((float)(pi + qi) * 0.03125f);
            acc = fmaf(t, wt[d * 4 + k], acc);
        }
    }
    float ew = 1.f / (1.f + __expf(-acc));
    unsigned entry = ((unsigned)srcg << 14) | (unsigned)(ew * 16383.f + 0.5f);
    int pos = atomicAdd(&cursor[dstg], 1);
    csr[pos] = entry;
}

// ---------------------------------------------------------------- fused propagation (2 rounds + final) with grid barriers
__device__ __forceinline__ void prop_half(const unsigned* __restrict__ m_in,
                                          unsigned* __restrict__ m_out,
                                          const int* __restrict__ off,
                                          const unsigned* __restrict__ csr,
                                          int idx) {
    int g = idx >> 1;
    int jp = (idx & 1) * 4;
    int p0 = off[g], p1 = off[g + 1];
    uint4 cur = *(const uint4*)&m_in[g * 8 + jp];
    float v0l = bflo(cur.x), v0h = bfhi(cur.x);
    float v1l = bflo(cur.y), v1h = bfhi(cur.y);
    float v2l = bflo(cur.z), v2h = bfhi(cur.z);
    float v3l = bflo(cur.w), v3h = bfhi(cur.w);
    int p = p0;
    for (; p + 1 < p1; p += 2) {
        unsigned e0 = csr[p], e1 = csr[p + 1];
        uint4 s0 = *(const uint4*)&m_in[(e0 >> 14) * 8 + jp];
        uint4 s1 = *(const uint4*)&m_in[(e1 >> 14) * 8 + jp];
        float w0 = (float)(e0 & 16383u) * (1.f / 16383.f);
        float w1 = (float)(e1 & 16383u) * (1.f / 16383.f);
        v0l = fmaxf(v0l, fmaxf(bflo(s0.x) * w0, bflo(s1.x) * w1));
        v0h = fmaxf(v0h, fmaxf(bfhi(s0.x) * w0, bfhi(s1.x) * w1));
        v1l = fmaxf(v1l, fmaxf(bflo(s0.y) * w0, bflo(s1.y) * w1));
        v1h = fmaxf(v1h, fmaxf(bfhi(s0.y) * w0, bfhi(s1.y) * w1));
        v2l = fmaxf(v2l, fmaxf(bflo(s0.z) * w0, bflo(s1.z) * w1));
        v2h = fmaxf(v2h, fmaxf(bfhi(s0.z) * w0, bfhi(s1.z) * w1));
        v3l = fmaxf(v3l, fmaxf(bflo(s0.w) * w0, bflo(s1.w) * w1));
        v3h = fmaxf(v3h, fmaxf(bfhi(s0.w) * w0, bfhi(s1.w) * w1));
    }
    if (p < p1) {
        unsigned e0 = csr[p];
        uint4 s0 = *(const uint4*)&m_in[(e0 >> 14) * 8 + jp];
        float w0 = (float)(e0 & 16383u) * (1.f / 16383.f);
        v0l = fmaxf(v0l, bflo(s0.x) * w0);
        v0h = fmaxf(v0h, bfhi(s0.x) * w0);
        v1l = fmaxf(v1l, bflo(s0.y) * w0);
        v1h = fmaxf(v1h, bfhi(s0.y) * w0);
        v2l = fmaxf(v2l, bflo(s0.z) * w0);
        v2h = fmaxf(v2h, bfhi(s0.z) * w0);
        v3l = fmaxf(v3l, bflo(s0.w) * w0);
        v3h = fmaxf(v3h, bfhi(s0.w) * w0);
    }
    uint4 o4;
    o4.x = packbf(v0l, v0h);
    o4.y = packbf(v1l, v1h);
    o4.z = packbf(v2l, v2h);
    o4.w = packbf(v3l, v3h);
    *(uint4*)&m_out[g * 8 + jp] = o4;
}

__device__ __forceinline__ void grid_bar(int* flag) {
    __syncthreads();
    if (threadIdx.x == 0) {
        __threadfence();
        atomicAdd(flag, 1);
        while (__hip_atomic_load(flag, __ATOMIC_RELAXED, __HIP_MEMORY_SCOPE_AGENT) < PROP_NB) {}
        __threadfence();
    }
    __syncthreads();
}

__global__ __launch_bounds__(256, 4) void k_prop(unsigned* __restrict__ m_a,
                                                 unsigned* __restrict__ m_b,
                                                 const int* __restrict__ off,
                                                 const unsigned* __restrict__ csr,
                                                 int* __restrict__ flags,
                                                 float* __restrict__ out) {
    const int t0 = (int)blockIdx.x * 256 + threadIdx.x;
    const int STRIDE = PROP_NB * 256;
    // round 1: m_a -> m_b
    for (int idx = t0; idx < 2 * GN; idx += STRIDE) prop_half(m_a, m_b, off, csr, idx);
    grid_bar(&flags[0]);
    // round 2: m_b -> m_a
    for (int idx = t0; idx < 2 * GN; idx += STRIDE) prop_half(m_b, m_a, off, csr, idx);
    grid_bar(&flags[1]);
    // round 3 fused with branch combine: m_a -> out (fp32)
    for (int idx = t0; idx < 2 * NNODES; idx += STRIDE) {
        int g = idx >> 1;
        int jp = (idx & 1) * 4;
        uint4 c0 = *(const uint4*)&m_a[g * 8 + jp];
        uint4 c1 = *(const uint4*)&m_a[(g + NNODES) * 8 + jp];
        float v0l = fmaxf(bflo(c0.x), bflo(c1.x)), v0h = fmaxf(bfhi(c0.x), bfhi(c1.x));
        float v1l = fmaxf(bflo(c0.y), bflo(c1.y)), v1h = fmaxf(bfhi(c0.y), bfhi(c1.y));
        float v2l = fmaxf(bflo(c0.z), bflo(c1.z)), v2h = fmaxf(bfhi(c0.z), bfhi(c1.z));
        float v3l = fmaxf(bflo(c0.w), bflo(c1.w)), v3h = fmaxf(bfhi(c0.w), bfhi(c1.w));
#pragma unroll
        for (int br = 0; br < 2; ++br) {
            int gg = g + br * NNODES;
            int p0 = off[gg], p1 = off[gg + 1];
            for (int p = p0; p < p1; ++p) {
                unsigned e0 = csr[p];
                uint4 s0 = *(const uint4*)&m_a[(e0 >> 14) * 8 + jp];
                float w0 = (float)(e0 & 16383u) * (1.f / 16383.f);
                v0l = fmaxf(v0l, bflo(s0.x) * w0);
                v0h = fmaxf(v0h, bfhi(s0.x) * w0);
                v1l = fmaxf(v1l, bflo(s0.y) * w0);
                v1h = fmaxf(v1h, bfhi(s0.y) * w0);
                v2l = fmaxf(v2l, bflo(s0.z) * w0);
                v2h = fmaxf(v2h, bfhi(s0.z) * w0);
                v3l = fmaxf(v3l, bflo(s0.w) * w0);
                v3h = fmaxf(v3h, bfhi(s0.w) * w0);
            }
        }
        float* op = out + (size_t)g * 16 + jp * 2;
        *(float4*)op = make_float4(v0l, v0h, v1l, v1h);
        *(float4*)(op + 4) = make_float4(v2l, v2h, v3l, v3h);
    }
}

extern "C" void kernel_launch(void* const* d_in, const int* in_sizes, int n_in,
                              void* d_out, int out_size, void* d_ws, size_t ws_size,
                              hipStream_t stream) {
    const float* x     = (const float*)d_in[0];
    const float* mask  = (const float*)d_in[1];
    const int*   sei   = (const int*)d_in[2];
    const int*   dei   = (const int*)d_in[3];
    const float* sattr = (const float*)d_in[4];
    const float* dattr = (const float*)d_in[5];
    const float* Wt    = (const float*)d_in[6];
    const float* bt    = (const float*)d_in[7];
    const float* Wp    = (const float*)d_in[8];
    const float* bp    = (const float*)d_in[9];
    const float* Wd    = (const float*)d_in[10];
    const float* bd    = (const float*)d_in[11];
    float* out = (float*)d_out;

    char* ws = (char*)d_ws;
    size_t o = 0;
    auto take = [&](size_t bytes) -> char* {
        char* p = ws + o;
        o = (o + bytes + 255) & ~(size_t)255;
        return p;
    };
    char* pq      = take((size_t)PQ_BLOCKS * 4096);
    int* counts   = (int*)take((size_t)GNP * 4 + 256);  // flag area right after counts
    int* scanflag = counts + GNP;
    int* propflags = counts + GNP + 1;                  // flags[0], flags[1]
    int* off      = (int*)take((size_t)GNP * 4);
    int* cursor   = (int*)take((size_t)GNP * 4);
    int* bsum     = (int*)take(256 * 4);
    unsigned* csr = (unsigned*)take((size_t)ETOT * 4);
    unsigned* m_a = (unsigned*)take((size_t)GN8 * 4);
    unsigned* m_b = (unsigned*)take((size_t)GN8 * 4);

    hipMemsetAsync(counts, 0, (size_t)GNP * 4 + 256, stream);
    k_pq<<<PQ_BLOCKS, 256, 0, stream>>>(x, Wt, bt, pq);
    k_initcount<<<3125 + 2 * CNT_BLK, 256, 0, stream>>>(mask, m_a, sei + ES, dei + ED, counts);
    k_scanfused<<<SCAN_BLOCKS, 256, 0, stream>>>(counts, bsum, scanflag, off, cursor);
    k_ewfill<<<(ETOT + 255) / 256, 256, 0, stream>>>(pq,
        sei, sei + ES, dei, dei + ED, sattr, dattr, Wp, bp, Wd, bd, cursor, csr);
    k_prop<<<PROP_NB, 256, 0, stream>>>(m_a, m_b, off, csr, propflags, out);
}

// Round 11
// 324.534 us; speedup vs baseline: 1.8990x; 1.8990x over previous
//
#include <hip/hip_runtime.h>
#include <hip/hip_bf16.h>
#include <stdint.h>

#define NNODES 100000
#define HID 128
#define TSZ 32
#define MDIM 16
#define ES 600000
#define ED 600000
#define ETOT (ES + ED)
#define GN (2 * NNODES)     // both branches share one node index space
#define GNP 200704          // 196 * 1024, padded for the scan
#define SCAN_BLOCKS 196
#define NP8 (NNODES * 8)    // 800,000 packed pairs per branch
#define GN8 (GN * 8)        // 1,600,000 packed pairs total
#define PQ_BLOCKS 1563      // ceil(NNODES/64)
#define CNT_BLK 586         // ceil(600000/1024) count blocks per edge set

typedef unsigned short ushort_t;

__device__ __forceinline__ float bflo(unsigned u) { return __uint_as_float(u << 16); }
__device__ __forceinline__ float bfhi(unsigned u) { return __uint_as_float(u & 0xffff0000u); }

// RNE fp32 -> bf16 (finite inputs only)
__device__ __forceinline__ unsigned f2bf(float f) {
    unsigned u = __float_as_uint(f);
    return (u + 0x7FFFu + ((u >> 16) & 1u)) >> 16;
}
__device__ __forceinline__ unsigned packbf(float lo, float hi) {
    return f2bf(lo) | (f2bf(hi) << 16);
}

__device__ __forceinline__ float tanh_fast(float v) {
    float z = __expf(2.f * v);
    return 1.f - 2.f / (z + 1.f);
}

// ---------------------------------------------------------------- fused prep: PQ GEMM + init m + degree count
// blocks [0,1563): int8 PQ tile; [1563,1563+3125): init m_a; rest: degree counts.
__global__ __launch_bounds__(256) void k_prep(const float* __restrict__ x,
                                              const float* __restrict__ Wt,
                                              const float* __restrict__ bt,
                                              char* __restrict__ pq,
                                              const float* __restrict__ mask,
                                              unsigned* __restrict__ m_a,
                                              const int* __restrict__ sdst,
                                              const int* __restrict__ ddst,
                                              int* __restrict__ counts) {
    __shared__ float xs[64][132];
    __shared__ float wl[64][130];
    const int tid = threadIdx.x;
    int b = (int)blockIdx.x;

    if (b < PQ_BLOCKS) {
        const int n0 = b * 64;
        for (int i = tid; i < 4096; i += 256) {
            int h = i >> 5, c = i & 31;
            float a = Wt[i];
            float bv2 = Wt[4096 + i];
            wl[c][h] = a;
            wl[c + 32][h] = bv2;
        }
        const float4* xsrc = (const float4*)(x + (size_t)n0 * 128);
#pragma unroll
        for (int i = 0; i < 8; ++i) {
            int idx = tid + 256 * i;
            int node = idx >> 5;
            int rem = idx & 31;
            if (n0 + node < NNODES) {
                float4 v = xsrc[idx];
                *(float4*)&xs[node][rem * 4] = v;
            }
        }
        __syncthreads();

        const int l = tid & 63;
        const int w = tid >> 6;
        const int c0 = l & 15;
        const int ng = w * 16 + (l >> 4) * 4;
        float acc[4][4] = {};
#pragma unroll 4
        for (int h = 0; h < 128; h += 2) {
            float2 xv[4], wv[4];
#pragma unroll
            for (int m = 0; m < 4; ++m) xv[m] = *(const float2*)&xs[ng + m][h];
#pragma unroll
            for (int m = 0; m < 4; ++m) wv[m] = *(const float2*)&wl[c0 + 16 * m][h];
#pragma unroll
            for (int a = 0; a < 4; ++a)
#pragma unroll
                for (int c = 0; c < 4; ++c)
                    acc[a][c] = fmaf(xv[a].y, wv[c].y, fmaf(xv[a].x, wv[c].x, acc[a][c]));
        }
        float bv[4];
#pragma unroll
        for (int c = 0; c < 4; ++c) {
            int cc = c0 + 16 * c;
            bv[c] = (cc < 32) ? bt[cc] : 0.f;
        }
        __syncthreads();
        char* buf = (char*)&xs[0][0];
#pragma unroll
        for (int a = 0; a < 4; ++a) {
#pragma unroll
            for (int c = 0; c < 4; ++c) {
                float v = acc[a][c] + bv[c];
                int q = __float2int_rn(v * 32.f);
                q = max(-127, min(127, q));
                buf[(ng + a) * 64 + c0 + 16 * c] = (char)q;
            }
        }
        __syncthreads();
        uint4 v4 = ((const uint4*)buf)[tid];
        ((uint4*)(pq + (size_t)b * 4096))[tid] = v4;
        return;
    }
    b -= PQ_BLOCKS;
    if (b < 3125) {
        int idx = b * 256 + tid;           // < NP8 exactly
        float2 v = ((const float2*)mask)[idx];
        unsigned p = packbf(v.x, v.y);
        m_a[idx] = p;
        m_a[NP8 + idx] = p;
        return;
    }
    b -= 3125;
    const int* dst;
    int add;
    if (b < CNT_BLK) { dst = sdst; add = 0; }
    else { b -= CNT_BLK; dst = ddst; add = NNODES; }
    int e0 = (b * 256 + tid) * 4;
    if (e0 + 4 <= 600000) {
        int4 d = *(const int4*)(dst + e0);
        atomicAdd(&counts[d.x + add], 1);
        atomicAdd(&counts[d.y + add], 1);
        atomicAdd(&counts[d.z + add], 1);
        atomicAdd(&counts[d.w + add], 1);
    } else {
        for (int e = e0; e < 600000; ++e) atomicAdd(&counts[dst[e] + add], 1);
    }
}

// ---------------------------------------------------------------- scan (3 kernels, no spinning)
__global__ __launch_bounds__(256) void k_scan1(const int* __restrict__ counts,
                                               int* __restrict__ bsum) {
    __shared__ int sh[256];
    int tid = threadIdx.x;
    int4 v = ((const int4*)counts)[blockIdx.x * 256 + tid];
    sh[tid] = v.x + v.y + v.z + v.w;
    __syncthreads();
    for (int o = 128; o > 0; o >>= 1) {
        if (tid < o) sh[tid] += sh[tid + o];
        __syncthreads();
    }
    if (tid == 0) bsum[blockIdx.x] = sh[0];
}

__global__ __launch_bounds__(256) void k_scan2(const int* __restrict__ bsum,
                                               int* __restrict__ prefix) {
    __shared__ int sh[256];
    int tid = threadIdx.x;
    int v = (tid < SCAN_BLOCKS) ? bsum[tid] : 0;
    sh[tid] = v;
    __syncthreads();
    for (int o = 1; o < 256; o <<= 1) {
        int add = (tid >= o) ? sh[tid - o] : 0;
        __syncthreads();
        sh[tid] += add;
        __syncthreads();
    }
    prefix[tid] = sh[tid] - v; // exclusive
}

__global__ __launch_bounds__(256) void k_scan3(const int* __restrict__ counts,
                                               const int* __restrict__ prefix,
                                               int* __restrict__ off,
                                               int* __restrict__ cursor) {
    __shared__ int sh[256];
    int tid = threadIdx.x;
    int4 v = ((const int4*)counts)[blockIdx.x * 256 + tid];
    int tot = v.x + v.y + v.z + v.w;
    sh[tid] = tot;
    __syncthreads();
    for (int o = 1; o < 256; o <<= 1) {
        int add = (tid >= o) ? sh[tid - o] : 0;
        __syncthreads();
        sh[tid] += add;
        __syncthreads();
    }
    int excl = sh[tid] - tot + prefix[blockIdx.x];
    int4 o4;
    o4.x = excl;
    o4.y = o4.x + v.x;
    o4.z = o4.y + v.y;
    o4.w = o4.z + v.z;
    ((int4*)off)[blockIdx.x * 256 + tid] = o4;
    ((int4*)cursor)[blockIdx.x * 256 + tid] = o4;
}

// ---------------------------------------------------------------- ew + CSR fill
__global__ void k_ewfill(const char* __restrict__ pq,
                         const int* __restrict__ ssrc, const int* __restrict__ sdst,
                         const int* __restrict__ dsrc, const int* __restrict__ ddst,
                         const float* __restrict__ sattr, const float* __restrict__ dattr,
                         const float* __restrict__ Wp, const float* __restrict__ bp,
                         const float* __restrict__ Wd, const float* __restrict__ bd,
                         int* __restrict__ cursor, unsigned* __restrict__ csr) {
    int e = blockIdx.x * 256 + threadIdx.x;
    if (e >= ETOT) return;
    int src, dst, dstg, srcg;
    float acc;
    const float* wt;
    if (e < ES) {
        src = ssrc[e];
        dst = sdst[e];
        dstg = dst;
        srcg = src;
        const float4 a = *(const float4*)(sattr + (size_t)e * 4);
        acc = bp[0] + a.x * Wp[0] + a.y * Wp[1] + a.z * Wp[2] + a.w * Wp[3];
        wt = Wp + 4;
    } else {
        int ed = e - ES;
        src = dsrc[ed];
        dst = ddst[ed];
        dstg = dst + NNODES;
        srcg = src + NNODES;
        acc = bd[0] + dattr[ed] * Wd[0];
        wt = Wd + 1;
    }
    const uint4* Pp = (const uint4*)(pq + (size_t)src * 64);
    const uint4* Qp = (const uint4*)(pq + (size_t)dst * 64 + 32);
    uint4 pa = Pp[0], pb = Pp[1];
    uint4 qa = Qp[0], qb = Qp[1];
    unsigned pw[8] = {pa.x, pa.y, pa.z, pa.w, pb.x, pb.y, pb.z, pb.w};
    unsigned qw[8] = {qa.x, qa.y, qa.z, qa.w, qb.x, qb.y, qb.z, qb.w};
#pragma unroll
    for (int d = 0; d < 8; ++d) {
        unsigned a = pw[d], b = qw[d];
#pragma unroll
        for (int k = 0; k < 4; ++k) {
            int pi = (int)(char)(a >> (8 * k));
            int qi = (int)(char)(b >> (8 * k));
            float t = tanh_fast((float)(pi + qi) * 0.03125f);
            acc = fmaf(t, wt[d * 4 + k], acc);
        }
    }
    float ew = 1.f / (1.f + __expf(-acc));
    unsigned entry = ((unsigned)srcg << 14) | (unsigned)(ew * 16383.f + 0.5f);
    int pos = atomicAdd(&cursor[dstg], 1);
    csr[pos] = entry;
}

// ---------------------------------------------------------------- propagation round (2 thr/node, uint4 gathers)
template <int TAG>
__global__ __launch_bounds__(256) void k_round_t(const unsigned* __restrict__ m_in,
                                                 unsigned* __restrict__ m_out,
                                                 const int* __restrict__ off,
                                                 const unsigned* __restrict__ csr) {
    int idx = blockIdx.x * 256 + threadIdx.x;   // 2*GN = 400000 threads
    if (idx >= 2 * GN) return;
    int g = idx >> 1;
    int jp = (idx & 1) * 4;
    int p0 = off[g], p1 = off[g + 1];
    uint4 cur = *(const uint4*)&m_in[g * 8 + jp];
    float v0l = bflo(cur.x), v0h = bfhi(cur.x);
    float v1l = bflo(cur.y), v1h = bfhi(cur.y);
    float v2l = bflo(cur.z), v2h = bfhi(cur.z);
    float v3l = bflo(cur.w), v3h = bfhi(cur.w);
    int p = p0;
    for (; p + 1 < p1; p += 2) {
        unsigned e0 = csr[p], e1 = csr[p + 1];
        uint4 s0 = *(const uint4*)&m_in[(e0 >> 14) * 8 + jp];
        uint4 s1 = *(const uint4*)&m_in[(e1 >> 14) * 8 + jp];
        float w0 = (float)(e0 & 16383u) * (1.f / 16383.f);
        float w1 = (float)(e1 & 16383u) * (1.f / 16383.f);
        v0l = fmaxf(v0l, fmaxf(bflo(s0.x) * w0, bflo(s1.x) * w1));
        v0h = fmaxf(v0h, fmaxf(bfhi(s0.x) * w0, bfhi(s1.x) * w1));
        v1l = fmaxf(v1l, fmaxf(bflo(s0.y) * w0, bflo(s1.y) * w1));
        v1h = fmaxf(v1h, fmaxf(bfhi(s0.y) * w0, bfhi(s1.y) * w1));
        v2l = fmaxf(v2l, fmaxf(bflo(s0.z) * w0, bflo(s1.z) * w1));
        v2h = fmaxf(v2h, fmaxf(bfhi(s0.z) * w0, bfhi(s1.z) * w1));
        v3l = fmaxf(v3l, fmaxf(bflo(s0.w) * w0, bflo(s1.w) * w1));
        v3h = fmaxf(v3h, fmaxf(bfhi(s0.w) * w0, bfhi(s1.w) * w1));
    }
    if (p < p1) {
        unsigned e0 = csr[p];
        uint4 s0 = *(const uint4*)&m_in[(e0 >> 14) * 8 + jp];
        float w0 = (float)(e0 & 16383u) * (1.f / 16383.f);
        v0l = fmaxf(v0l, bflo(s0.x) * w0);
        v0h = fmaxf(v0h, bfhi(s0.x) * w0);
        v1l = fmaxf(v1l, bflo(s0.y) * w0);
        v1h = fmaxf(v1h, bfhi(s0.y) * w0);
        v2l = fmaxf(v2l, bflo(s0.z) * w0);
        v2h = fmaxf(v2h, bfhi(s0.z) * w0);
        v3l = fmaxf(v3l, bflo(s0.w) * w0);
        v3h = fmaxf(v3h, bfhi(s0.w) * w0);
    }
    uint4 o4;
    o4.x = packbf(v0l, v0h);
    o4.y = packbf(v1l, v1h);
    o4.z = packbf(v2l, v2h);
    o4.w = packbf(v3l, v3h);
    *(uint4*)&m_out[g * 8 + jp] = o4;
}

// ---------------------------------------------------------------- final round fused with branch combine
__global__ __launch_bounds__(256) void k_round_final(const unsigned* __restrict__ m_in,
                                                     float* __restrict__ out,
                                                     const int* __restrict__ off,
                                                     const unsigned* __restrict__ csr) {
    int idx = blockIdx.x * 256 + threadIdx.x;   // 2*NNODES = 200000 threads
    if (idx >= 2 * NNODES) return;
    int g = idx >> 1;
    int jp = (idx & 1) * 4;
    uint4 c0 = *(const uint4*)&m_in[g * 8 + jp];
    uint4 c1 = *(const uint4*)&m_in[(g + NNODES) * 8 + jp];
    float v0l = fmaxf(bflo(c0.x), bflo(c1.x)), v0h = fmaxf(bfhi(c0.x), bfhi(c1.x));
    float v1l = fmaxf(bflo(c0.y), bflo(c1.y)), v1h = fmaxf(bfhi(c0.y), bfhi(c1.y));
    float v2l = fmaxf(bflo(c0.z), bflo(c1.z)), v2h = fmaxf(bfhi(c0.z), bfhi(c1.z));
    float v3l = fmaxf(bflo(c0.w), bflo(c1.w)), v3h = fmaxf(bfhi(c0.w), bfhi(c1.w));
#pragma unroll
    for (int br = 0; br < 2; ++br) {
        int gg = g + br * NNODES;
        int p0 = off[gg], p1 = off[gg + 1];
        for (int p = p0; p < p1; ++p) {
            unsigned e0 = csr[p];
            uint4 s0 = *(const uint4*)&m_in[(e0 >> 14) * 8 + jp];
            float w0 = (float)(e0 & 16383u) * (1.f / 16383.f);
            v0l = fmaxf(v0l, bflo(s0.x) * w0);
            v0h = fmaxf(v0h, bfhi(s0.x) * w0);
            v1l = fmaxf(v1l, bflo(s0.y) * w0);
            v1h = fmaxf(v1h, bfhi(s0.y) * w0);
            v2l = fmaxf(v2l, bflo(s0.z) * w0);
            v2h = fmaxf(v2h, bfhi(s0.z) * w0);
            v3l = fmaxf(v3l, bflo(s0.w) * w0);
            v3h = fmaxf(v3h, bfhi(s0.w) * w0);
        }
    }
    float* op = out + (size_t)g * 16 + jp * 2;
    *(float4*)op = make_float4(v0l, v0h, v1l, v1h);
    *(float4*)(op + 4) = make_float4(v2l, v2h, v3l, v3h);
}

extern "C" void kernel_launch(void* const* d_in, const int* in_sizes, int n_in,
                              void* d_out, int out_size, void* d_ws, size_t ws_size,
                              hipStream_t stream) {
    const float* x     = (const float*)d_in[0];
    const float* mask  = (const float*)d_in[1];
    const int*   sei   = (const int*)d_in[2];
    const int*   dei   = (const int*)d_in[3];
    const float* sattr = (const float*)d_in[4];
    const float* dattr = (const float*)d_in[5];
    const float* Wt    = (const float*)d_in[6];
    const float* bt    = (const float*)d_in[7];
    const float* Wp    = (const float*)d_in[8];
    const float* bp    = (const float*)d_in[9];
    const float* Wd    = (const float*)d_in[10];
    const float* bd    = (const float*)d_in[11];
    float* out = (float*)d_out;

    char* ws = (char*)d_ws;
    size_t o = 0;
    auto take = [&](size_t bytes) -> char* {
        char* p = ws + o;
        o = (o + bytes + 255) & ~(size_t)255;
        return p;
    };
    char* pq      = take((size_t)PQ_BLOCKS * 4096);
    int* counts   = (int*)take((size_t)GNP * 4);
    int* off      = (int*)take((size_t)GNP * 4);
    int* cursor   = (int*)take((size_t)GNP * 4);
    int* bsum     = (int*)take(256 * 4);
    int* prefix   = (int*)take(256 * 4);
    unsigned* csr = (unsigned*)take((size_t)ETOT * 4);
    unsigned* m_a = (unsigned*)take((size_t)GN8 * 4);
    unsigned* m_b = (unsigned*)take((size_t)GN8 * 4);

    hipMemsetAsync(counts, 0, (size_t)GNP * 4, stream);
    k_prep<<<PQ_BLOCKS + 3125 + 2 * CNT_BLK, 256, 0, stream>>>(
        x, Wt, bt, pq, mask, m_a, sei + ES, dei + ED, counts);
    k_scan1<<<SCAN_BLOCKS, 256, 0, stream>>>(counts, bsum);
    k_scan2<<<1, 256, 0, stream>>>(bsum, prefix);
    k_scan3<<<SCAN_BLOCKS, 256, 0, stream>>>(counts, prefix, off, cursor);
    k_ewfill<<<(ETOT + 255) / 256, 256, 0, stream>>>(pq,
        sei, sei + ES, dei, dei + ED, sattr, dattr, Wp, bp, Wd, bd, cursor, csr);
    k_round_t<0><<<(2 * GN + 255) / 256, 256, 0, stream>>>(m_a, m_b, off, csr);
    k_round_t<1><<<(2 * GN + 255) / 256, 256, 0, stream>>>(m_b, m_a, off, csr);
    k_round_final<<<(2 * NNODES + 255) / 256, 256, 0, stream>>>(m_a, out, off, csr);
}